// Round 6
// baseline (3994.377 us; speedup 1.0000x reference)
//
#include <hip/hip_runtime.h>

#define BB 64
#define TT 4096
#define HH 256
#define NTOK (BB * TT)

typedef _Float16 f16;
typedef _Float16 f16x8 __attribute__((ext_vector_type(8)));
typedef float f32x4 __attribute__((ext_vector_type(4)));
typedef unsigned int uint;
typedef unsigned short ushort;
typedef uint uint4v __attribute__((ext_vector_type(4)));

__device__ __forceinline__ uint packf16(float a, float b) {  // RNE pack (prep only)
    ushort lo = __builtin_bit_cast(ushort, (f16)a);
    ushort hi = __builtin_bit_cast(ushort, (f16)b);
    return (uint)lo | ((uint)hi << 16);
}

__device__ __forceinline__ uint dpp_xor1_u(uint v) {  // quad_perm [1,0,3,2]: lane ^ 1
    return (uint)__builtin_amdgcn_update_dpp(0, (int)v, 0xB1, 0xF, 0xF, true);
}

// ============ prep: W_hh -> MFMA A-frags, K-split layout ============
// RNN wave w (K-range [64w,64w+64)), lane l, frag fi = mt*2+ks (mt<16 m-tiles, ks<2):
// elem j: A[m=16mt+(lane&15)][k] = Whh[16mt+(lane&15)][64w+32ks+8*(lane>>4)+j].
// Wsw[(w*64+lane)*32 + fi].
__global__ __launch_bounds__(256) void rnn_wswz_kernel(const float* __restrict__ Whh,
                                                       uint4v* __restrict__ Wsw) {
    int gid = blockIdx.x * 256 + threadIdx.x;  // 8192 uint4 = 128 KiB
    if (gid >= 8192) return;
    int tid = gid >> 5, fi = gid & 31;
    int mt = fi >> 1, ks = fi & 1;
    int lane = tid & 63, w = tid >> 6;
    int row = 16 * mt + (lane & 15);
    int col = 64 * w + 32 * ks + 8 * (lane >> 4);
    const float* p = Whh + row * 256 + col;
    uint4v v;
    v.x = packf16(p[0], p[1]);
    v.y = packf16(p[2], p[3]);
    v.z = packf16(p[4], p[5]);
    v.w = packf16(p[6], p[7]);
    Wsw[gid] = v;
}

// ============ prep: MLP weights -> MFMA B-fragment-major layout ============
__global__ __launch_bounds__(256) void bfrag_prep_kernel(const float* __restrict__ W,
                                                         uint4v* __restrict__ dst,
                                                         int N, int Kreal, int KS, int NT) {
    int gid = blockIdx.x * 256 + threadIdx.x;
    if (gid >= NT * KS * 64) return;
    int lane = gid & 63;
    int t = gid >> 6;
    int ks = t % KS, nt = t / KS;
    int n = nt * 16 + (lane & 15);
    int kb = ks * 32 + (lane >> 4) * 8;
    float f[8];
#pragma unroll
    for (int j = 0; j < 8; ++j) {
        int k = kb + j;
        f[j] = (n < N && k < Kreal) ? W[n * Kreal + k] : 0.f;
    }
    uint4v v;
    v.x = packf16(f[0], f[1]);
    v.y = packf16(f[2], f[3]);
    v.z = packf16(f[4], f[5]);
    v.w = packf16(f[6], f[7]);
    dst[gid] = v;
}

// ============ RNN: 64 blocks x 256 threads, K-split partial-sum MFMA ============
// Wave w owns output dims AND K-range [64w,64w+64); lane l keeps h[64w+l] in reg.
// Per step: intra-wave bpermute redistributes h pairs -> B-frags (NO barrier),
// 32 MFMAs (16 mt x 2 ks, dep depth 2) compute partial[0..256) over wave's K-slice,
// bl==0 lanes write partials to LDS, ONE barrier, each lane reads its dim's 4
// partials (consecutive dwords, conflict-free) + xw (scalar x loads) + tanh.
// h never round-trips LDS; x never staged; ht stored per-step (128B/wave coalesced).
__global__ __launch_bounds__(256) __attribute__((amdgpu_waves_per_eu(1, 1))) void rnn_kernel(
        const float* __restrict__ x, const uint4v* __restrict__ Wsw,
        const float* __restrict__ Wih, const float* __restrict__ bih,
        const float* __restrict__ bhh, f16* __restrict__ ht, float* __restrict__ hlast) {
    const int b = blockIdx.x, tid = threadIdx.x;
    const int lane = tid & 63, w = tid >> 6;
    const int q = lane >> 4, bl = lane & 15;
    const int d = 64 * w + lane;  // this lane's hidden dim
    __shared__ float pbuf[2][4][256];  // [pingpong][wave][dim] f32 partials

    uint4v wv[32];  // A-frags: wv[mt*2+ks]; unpinned (AGPR-resident is fine for MFMA)
    {
        const uint4v* wp = Wsw + (size_t)tid * 32;
#pragma unroll
        for (int i = 0; i < 32; ++i) wv[i] = wp[i];
    }

    float wih[7];
#pragma unroll
    for (int i = 0; i < 7; ++i) wih[i] = Wih[d * 7 + i];
    const float bias = bih[d] + bhh[d];

    const float* xb = x + (size_t)b * TT * 12;
    f16* htp = ht + (size_t)b * TT * 256 + d;
    const int bidx = (lane >> 4) << 5;  // byte addr of this lane-group's h-pair base

    uint hpk = 0;  // packed f16x2 {h[64w+2e], h[64w+2e+1]} for this lane's pair

#define RNN_STEP(BUF, T)                                                                   \
    {                                                                                      \
        const float* xt = xb + (size_t)(T) * 12;                                           \
        /* B-frags via intra-wave bpermute of packed h pairs */                            \
        uint4v bv0, bv1;                                                                   \
        bv0.x = (uint)__builtin_amdgcn_ds_bpermute(bidx + 0, (int)hpk);                    \
        bv0.y = (uint)__builtin_amdgcn_ds_bpermute(bidx + 8, (int)hpk);                    \
        bv0.z = (uint)__builtin_amdgcn_ds_bpermute(bidx + 16, (int)hpk);                   \
        bv0.w = (uint)__builtin_amdgcn_ds_bpermute(bidx + 24, (int)hpk);                   \
        bv1.x = (uint)__builtin_amdgcn_ds_bpermute(bidx + 128, (int)hpk);                  \
        bv1.y = (uint)__builtin_amdgcn_ds_bpermute(bidx + 136, (int)hpk);                  \
        bv1.z = (uint)__builtin_amdgcn_ds_bpermute(bidx + 144, (int)hpk);                  \
        bv1.w = (uint)__builtin_amdgcn_ds_bpermute(bidx + 152, (int)hpk);                  \
        f16x8 hb0 = __builtin_bit_cast(f16x8, bv0);                                        \
        f16x8 hb1 = __builtin_bit_cast(f16x8, bv1);                                        \
        f32x4 acc[16];                                                                     \
        _Pragma("unroll") for (int mt = 0; mt < 16; ++mt) acc[mt] =                        \
            __builtin_amdgcn_mfma_f32_16x16x32_f16(__builtin_bit_cast(f16x8, wv[2 * mt]),  \
                                                   hb0, (f32x4){0.f, 0.f, 0.f, 0.f}, 0, 0, 0); \
        _Pragma("unroll") for (int mt = 0; mt < 16; ++mt) acc[mt] =                        \
            __builtin_amdgcn_mfma_f32_16x16x32_f16(                                        \
                __builtin_bit_cast(f16x8, wv[2 * mt + 1]), hb1, acc[mt], 0, 0, 0);         \
        /* partial write: lanes bl==0 (q=0..3) cover dims 16mt+4q+r */                     \
        if (bl == 0) {                                                                     \
            float* pw = &pbuf[BUF][w][q * 4];                                              \
            _Pragma("unroll") for (int mt = 0; mt < 16; ++mt)                              \
                *(f32x4*)(pw + mt * 16) = acc[mt];                                         \
        }                                                                                  \
        /* x contribution: wave-uniform scalar loads, hidden under MFMA phase */           \
        float xw = fmaf(xt[0], wih[0], bias);                                              \
        xw = fmaf(xt[1], wih[1], xw);                                                      \
        xw = fmaf(xt[2], wih[2], xw);                                                      \
        xw = fmaf(xt[3], wih[3], xw);                                                      \
        xw = fmaf(xt[4], wih[4], xw);                                                      \
        xw = fmaf(xt[5], wih[5], xw);                                                      \
        xw = fmaf(xt[6], wih[6], xw);                                                      \
        asm volatile("s_waitcnt lgkmcnt(0)\n\ts_barrier" ::: "memory");                    \
        /* reduce 4 partials for dim d: consecutive dwords, 2-way alias = free */          \
        const float* pr = &pbuf[BUF][0][d];                                                \
        float pre = ((pr[0] + pr[256]) + (pr[512] + pr[768])) + xw;                        \
        /* tanh(x) = 2/(1+2^(c*x)) - 1, c = -2*log2(e) */                                  \
        float e = __builtin_amdgcn_exp2f(-2.885390082f * pre);                             \
        float rr = __builtin_amdgcn_rcpf(1.0f + e);                                        \
        float hv = fmaf(2.0f, rr, -1.0f);                                                  \
        f16 hf = (f16)hv;                                                                  \
        htp[(size_t)(T) * 256] = hf;                                                       \
        if ((T) == TT - 1) hlast[b * 256 + d] = hv;                                        \
        /* pack pair {even,odd} into uint (both lanes of the pair hold it) */              \
        uint my = (uint)__builtin_bit_cast(ushort, hf);                                    \
        uint pt = dpp_xor1_u(my);                                                          \
        hpk = (lane & 1) ? ((my << 16) | pt) : ((pt << 16) | my);                          \
    }

    for (int t = 0; t < TT; t += 2) {
        RNN_STEP(0, t)
        RNN_STEP(1, t + 1)
    }
#undef RNN_STEP
}

// ============ MFMA MLP: 4096 blocks x 256 threads, 64 tokens/block ============
struct MlpB {
    const uint4v* bf[7];
    const float* bias[7];
};

template <int KS, int NT, bool MSPLIT>
__device__ __forceinline__ void mfma_layer(const uint4v* __restrict__ Bf,
                                           const float* __restrict__ bias, int Nreal,
                                           const uint4v* zin, uint4v* zout,
                                           int w, int lane, int m15, int q) {
    constexpr int NW = MSPLIT ? NT : (NT / 4);  // n-tiles per wave
    constexpr int MW = MSPLIT ? 1 : 4;          // m-tiles per wave
    const int ntb = MSPLIT ? 0 : w * NW;
    const int mtb = MSPLIT ? w : 0;
    f32x4 acc[MW][NW];
#pragma unroll
    for (int i = 0; i < MW; ++i)
#pragma unroll
        for (int j = 0; j < NW; ++j) acc[i][j] = (f32x4){0.f, 0.f, 0.f, 0.f};

#pragma unroll
    for (int ks = 0; ks < KS; ++ks) {
        f16x8 a[MW];
#pragma unroll
        for (int mt = 0; mt < MW; ++mt)
            a[mt] = __builtin_bit_cast(f16x8, zin[((mtb + mt) * 16 + m15) * 37 + ks * 4 + q]);
#pragma unroll
        for (int nt = 0; nt < NW; ++nt) {
            f16x8 b = __builtin_bit_cast(f16x8, Bf[((size_t)(ntb + nt) * KS + ks) * 64 + lane]);
#pragma unroll
            for (int mt = 0; mt < MW; ++mt)
                acc[mt][nt] =
                    __builtin_amdgcn_mfma_f32_16x16x32_f16(a[mt], b, acc[mt][nt], 0, 0, 0);
        }
    }
    f16* zo = (f16*)zout;
#pragma unroll
    for (int nt = 0; nt < NW; ++nt) {
        const int col = (ntb + nt) * 16 + m15;
        const float bv = (col < Nreal) ? bias[col] : 0.f;
#pragma unroll
        for (int mt = 0; mt < MW; ++mt) {
#pragma unroll
            for (int r = 0; r < 4; ++r) {
                float v = acc[mt][nt][r] + bv;
                v = fmaxf(v, 0.01f * v);  // leaky relu
                const int row = (mtb + mt) * 16 + q * 4 + r;
                zo[row * 296 + col] = (f16)v;
            }
        }
    }
}

__global__ __launch_bounds__(256) void mlp_kernel(const f16* __restrict__ ht,
                                                  const float* __restrict__ x,
                                                  MlpB P, float* __restrict__ out) {
    __shared__ uint4v z0[64 * 37];  // 37888 B each; ping-pong
    __shared__ uint4v z1[64 * 37];
    const int tid = threadIdx.x;
    const int w = tid >> 6, lane = tid & 63;
    const int m15 = lane & 15, q = lane >> 4;
    const int tok0 = blockIdx.x * 64;

    // stage z0 = [ht(256) | x_fixed(5) | 0-pad(27)] rows, 296-f16 stride
    for (int i = tid; i < 64 * 32; i += 256) {
        int r = i >> 5, u = i & 31;
        z0[r * 37 + u] = ((const uint4v*)(ht + (size_t)(tok0 + r) * 256))[u];
    }
    for (int i = tid; i < 64 * 5; i += 256) {
        int r = i / 5, u = 32 + (i % 5);
        uint4v v = {0u, 0u, 0u, 0u};
        if (u == 32) {
            const float* xp = x + (size_t)(tok0 + r) * 12 + 7;
            v.x = packf16(xp[0], xp[1]);
            v.y = packf16(xp[2], xp[3]);
            v.z = packf16(xp[4], 0.f);
        }
        z0[r * 37 + u] = v;
    }
    __syncthreads();

    mfma_layer<9, 16, false>(P.bf[0], P.bias[0], 256, z0, z1, w, lane, m15, q);
    __syncthreads();
    mfma_layer<8, 8, false>(P.bf[1], P.bias[1], 128, z1, z0, w, lane, m15, q);
    __syncthreads();
    mfma_layer<4, 4, false>(P.bf[2], P.bias[2], 64, z0, z1, w, lane, m15, q);
    __syncthreads();
    mfma_layer<2, 2, true>(P.bf[3], P.bias[3], 32, z1, z0, w, lane, m15, q);
    __syncthreads();
    mfma_layer<1, 1, true>(P.bf[4], P.bias[4], 16, z0, z1, w, lane, m15, q);
    __syncthreads();
    mfma_layer<1, 1, true>(P.bf[5], P.bias[5], 8, z1, z0, w, lane, m15, q);
    __syncthreads();

    // L6 head: K=8 (padded 32), N=7; no activation; fp32 out
    {
        f16x8 a = __builtin_bit_cast(f16x8, z0[(w * 16 + m15) * 37 + q]);
        f16x8 b = __builtin_bit_cast(f16x8, P.bf[6][lane]);
        f32x4 acc = (f32x4){0.f, 0.f, 0.f, 0.f};
        acc = __builtin_amdgcn_mfma_f32_16x16x32_f16(a, b, acc, 0, 0, 0);
        if (m15 < 7) {
            const float bv = P.bias[6][m15];
#pragma unroll
            for (int r = 0; r < 4; ++r)
                out[(size_t)(tok0 + w * 16 + q * 4 + r) * 7 + m15] = acc[r] + bv;
        }
    }
}

// ============ launch ============
extern "C" void kernel_launch(void* const* d_in, const int* in_sizes, int n_in,
                              void* d_out, int out_size, void* d_ws, size_t ws_size,
                              hipStream_t stream) {
    const float* x = (const float*)d_in[0];
    const float* Wih = (const float*)d_in[1];
    const float* Whh = (const float*)d_in[2];
    const float* bih = (const float*)d_in[3];
    const float* bhh = (const float*)d_in[4];
    const float* W[7];
    const float* bb[7];
    for (int j = 0; j < 7; ++j) {
        W[j] = (const float*)d_in[5 + 2 * j];
        bb[j] = (const float*)d_in[6 + 2 * j];
    }
    float* out = (float*)d_out;

    static const int Kd[7] = {261, 256, 128, 64, 32, 16, 8};
    static const int Nd[7] = {256, 128, 64, 32, 16, 8, 7};
    static const int KSd[7] = {9, 8, 4, 2, 1, 1, 1};
    static const int NTd[7] = {16, 8, 4, 2, 1, 1, 1};

    char* ws = (char*)d_ws;
    f16* ht = (f16*)ws;  // 128 MiB, plain [b][t][j]
    size_t off = (size_t)NTOK * HH * 2;
    uint4v* Wsw = (uint4v*)(ws + off);
    off += (size_t)8192 * 16;
    uint4v* bfp[7];
    for (int j = 0; j < 7; ++j) {
        bfp[j] = (uint4v*)(ws + off);
        off += (size_t)NTd[j] * KSd[j] * 64 * 16;
    }

    rnn_wswz_kernel<<<32, 256, 0, stream>>>(Whh, Wsw);
    for (int j = 0; j < 7; ++j) {
        int cnt = NTd[j] * KSd[j] * 64;
        bfrag_prep_kernel<<<(cnt + 255) / 256, 256, 0, stream>>>(W[j], bfp[j], Nd[j], Kd[j],
                                                                 KSd[j], NTd[j]);
    }

    rnn_kernel<<<BB, 256, 0, stream>>>(x, Wsw, Wih, bih, bhh, ht, out + (size_t)NTOK * 7);

    MlpB P;
    for (int j = 0; j < 7; ++j) {
        P.bf[j] = bfp[j];
        P.bias[j] = bb[j];
    }
    mlp_kernel<<<NTOK / 64, 256, 0, stream>>>(ht, x, P, out);
}

// Round 7
// 2537.323 us; speedup vs baseline: 1.5742x; 1.5742x over previous
//
#include <hip/hip_runtime.h>

#define BB 64
#define TT 4096
#define HH 256
#define NTOK (BB * TT)

typedef _Float16 f16;
typedef _Float16 f16x8 __attribute__((ext_vector_type(8)));
typedef float f32x4 __attribute__((ext_vector_type(4)));
typedef unsigned int uint;
typedef unsigned short ushort;
typedef uint uint4v __attribute__((ext_vector_type(4)));

__device__ __forceinline__ uint packf16(float a, float b) {  // RNE pack (prep only)
    ushort lo = __builtin_bit_cast(ushort, (f16)a);
    ushort hi = __builtin_bit_cast(ushort, (f16)b);
    return (uint)lo | ((uint)hi << 16);
}

__device__ __forceinline__ uint dpp_xor1_u(uint v) {  // quad_perm [1,0,3,2]: lane ^ 1
    return (uint)__builtin_amdgcn_update_dpp(0, (int)v, 0xB1, 0xF, 0xF, true);
}

// ============ prep: W_hh^T -> MFMA B-frags, K-split over 8 waves ============
// RNN wave w (K-slice [32w,32w+32)), lane l (q=l>>4, bl=l&15), frag mt (0..15):
// elem j: B[k=8q+j][n=bl] = Whh[16mt+bl][32w+8q+j].  Wsw[(w*64+l)*16 + mt].
__global__ __launch_bounds__(256) void rnn_wswz_kernel(const float* __restrict__ Whh,
                                                       uint4v* __restrict__ Wsw) {
    int gid = blockIdx.x * 256 + threadIdx.x;  // 8192 uint4 = 128 KiB
    if (gid >= 8192) return;
    int tid = gid >> 4, mt = gid & 15;
    int lane = tid & 63, w = tid >> 6;
    int row = 16 * mt + (lane & 15);           // Whh row = output dim
    int col = 32 * w + 8 * (lane >> 4);        // k base
    const float* p = Whh + row * 256 + col;
    uint4v v;
    v.x = packf16(p[0], p[1]);
    v.y = packf16(p[2], p[3]);
    v.z = packf16(p[4], p[5]);
    v.w = packf16(p[6], p[7]);
    Wsw[gid] = v;
}

// ============ prep: MLP weights -> MFMA B-fragment-major layout ============
__global__ __launch_bounds__(256) void bfrag_prep_kernel(const float* __restrict__ W,
                                                         uint4v* __restrict__ dst,
                                                         int N, int Kreal, int KS, int NT) {
    int gid = blockIdx.x * 256 + threadIdx.x;
    if (gid >= NT * KS * 64) return;
    int lane = gid & 63;
    int t = gid >> 6;
    int ks = t % KS, nt = t / KS;
    int n = nt * 16 + (lane & 15);
    int kb = ks * 32 + (lane >> 4) * 8;
    float f[8];
#pragma unroll
    for (int j = 0; j < 8; ++j) {
        int k = kb + j;
        f[j] = (n < N && k < Kreal) ? W[n * Kreal + k] : 0.f;
    }
    uint4v v;
    v.x = packf16(f[0], f[1]);
    v.y = packf16(f[2], f[3]);
    v.z = packf16(f[4], f[5]);
    v.w = packf16(f[6], f[7]);
    dst[gid] = v;
}

// ============ RNN: 64 blocks x 512 threads, operand-swapped K-split MFMA ============
// Wave w owns K-slice [32w,32w+32); lane l keeps h[32w+(l&31)] in reg (dup halves).
// Per step: 4 ds_bpermute build A-frag (h-slice bcast over m); 16 INDEPENDENT MFMAs
// B=W^T frag (64 pinned VGPRs) give lane(q,bl): acc_mt[r]=partial[16mt+bl] (all r,q dup);
// q==0 lanes pack 4 reg0s -> 4x ds_write_b128 to pbuf[w][bl][mt]; ONE barrier;
// each lane reads 8 partials for dim d=32w+(l&31) (bcast-paired, ~2-way), 7-add tree,
// + xw + tanh -> h stays in-lane. No h LDS round-trip, no extract tree, no reg spill.
__global__ __launch_bounds__(512) __attribute__((amdgpu_waves_per_eu(2, 2))) void rnn_kernel(
        const float* __restrict__ x, const uint4v* __restrict__ Wsw,
        const float* __restrict__ Wih, const float* __restrict__ bih,
        const float* __restrict__ bhh, f16* __restrict__ ht, float* __restrict__ hlast) {
    const int b = blockIdx.x, tid = threadIdx.x;
    const int lane = tid & 63, w = tid >> 6;   // 8 waves
    const int q = lane >> 4, bl = lane & 15;   // q in 0..3
    const int l32 = lane & 31;
    const int d = 32 * w + l32;                // dim this lane finalizes (dup in halves)
    const int mtw = 2 * w + (l32 >> 4);        // d>>4
    __shared__ float pbuf[2][8][16][20];       // [pingpong][wave][n=bl][mt(pad 20)] f32
    __shared__ uint4 xs[2][128];               // 64 timesteps x 32B, double-buffered

    uint4v wv[16];  // B-frags (W^T), wv[mt]; pinned: 64 VGPRs
    {
        const uint4v* wp = Wsw + (size_t)tid * 16;
#pragma unroll
        for (int i = 0; i < 16; ++i) wv[i] = wp[i];
    }
#pragma unroll
    for (int i = 0; i < 16; ++i) asm volatile("" : "+v"(wv[i]));

    float wih[7];
#pragma unroll
    for (int i = 0; i < 7; ++i) wih[i] = Wih[d * 7 + i];
    const float bias = bih[d] + bhh[d];

    const float* xb = x + (size_t)b * TT * 12;
    uint4 xpre = make_uint4(0, 0, 0, 0);
    if (tid < 128) {
        int row = tid >> 1, u = tid & 1;
        xs[0][row * 2 + u] = *(const uint4*)(xb + row * 12 + u * 4);
        xpre = *(const uint4*)(xb + (64 + row) * 12 + u * 4);
    }
    __syncthreads();

    f16* htp = ht + (size_t)b * TT * 256 + d;  // PLAIN layout [b][t][j]
    const int bidx = q << 5;  // bpermute byte base: pairs 4q+t live at lanes 8q+2t

    uint hpk = 0;  // packed f16x2 pair {h[32w+2P], h[32w+2P+1]}, P = (l&31)>>1; h0=0

#define RNN_STEP(BUF, T)                                                                    \
    {                                                                                       \
        const int tile = ((T) >> 6) & 1, tstep = (T)&63;                                    \
        /* A-frag: h[32w+8q+j] via 4 intra-wave bpermutes (pair-duplicated) */              \
        uint4v bv;                                                                          \
        bv.x = (uint)__builtin_amdgcn_ds_bpermute(bidx + 0, (int)hpk);                      \
        bv.y = (uint)__builtin_amdgcn_ds_bpermute(bidx + 8, (int)hpk);                      \
        bv.z = (uint)__builtin_amdgcn_ds_bpermute(bidx + 16, (int)hpk);                     \
        bv.w = (uint)__builtin_amdgcn_ds_bpermute(bidx + 24, (int)hpk);                     \
        f16x8 ha = __builtin_bit_cast(f16x8, bv);                                           \
        /* 16 independent MFMAs in 4 groups; pack+write per group (short acc liveness) */   \
        _Pragma("unroll") for (int g = 0; g < 4; ++g) {                                     \
            f32x4 a0 = __builtin_amdgcn_mfma_f32_16x16x32_f16(                              \
                ha, __builtin_bit_cast(f16x8, wv[4 * g + 0]), (f32x4){0.f, 0.f, 0.f, 0.f},  \
                0, 0, 0);                                                                   \
            f32x4 a1 = __builtin_amdgcn_mfma_f32_16x16x32_f16(                              \
                ha, __builtin_bit_cast(f16x8, wv[4 * g + 1]), (f32x4){0.f, 0.f, 0.f, 0.f},  \
                0, 0, 0);                                                                   \
            f32x4 a2 = __builtin_amdgcn_mfma_f32_16x16x32_f16(                              \
                ha, __builtin_bit_cast(f16x8, wv[4 * g + 2]), (f32x4){0.f, 0.f, 0.f, 0.f},  \
                0, 0, 0);                                                                   \
            f32x4 a3 = __builtin_amdgcn_mfma_f32_16x16x32_f16(                              \
                ha, __builtin_bit_cast(f16x8, wv[4 * g + 3]), (f32x4){0.f, 0.f, 0.f, 0.f},  \
                0, 0, 0);                                                                   \
            if (q == 0) {                                                                   \
                f32x4 qd = {a0[0], a1[0], a2[0], a3[0]};                                    \
                *(f32x4*)&pbuf[BUF][w][bl][4 * g] = qd;                                     \
            }                                                                               \
        }                                                                                   \
        /* x contribution: wave-uniform broadcast reads (VALU co-issues with MFMA) */       \
        const float4 xa = ((const float4*)xs[tile])[tstep * 2];                             \
        const float4 xc = ((const float4*)xs[tile])[tstep * 2 + 1];                         \
        float xw = fmaf(xa.x, wih[0], bias);                                                \
        xw = fmaf(xa.y, wih[1], xw);                                                        \
        xw = fmaf(xa.z, wih[2], xw);                                                        \
        xw = fmaf(xa.w, wih[3], xw);                                                        \
        xw = fmaf(xc.x, wih[4], xw);                                                        \
        xw = fmaf(xc.y, wih[5], xw);                                                        \
        xw = fmaf(xc.z, wih[6], xw);                                                        \
        if (tstep == 32 && tid < 128) {                                                     \
            int row = tid >> 1, u = tid & 1;                                                \
            xs[tile ^ 1][row * 2 + u] = xpre;                                               \
            int nt = ((T) & ~63) + 128 + row;                                               \
            if (nt > TT - 1) nt = TT - 1;                                                   \
            xpre = *(const uint4*)(xb + nt * 12 + u * 4);                                   \
        }                                                                                   \
        asm volatile("s_waitcnt lgkmcnt(0)\n\ts_barrier" ::: "memory");                     \
        /* reduce 8 wave-partials for dim d (half-dup -> broadcast, ~2-way banks) */        \
        float p0 = pbuf[BUF][0][bl][mtw], p1 = pbuf[BUF][1][bl][mtw];                       \
        float p2 = pbuf[BUF][2][bl][mtw], p3 = pbuf[BUF][3][bl][mtw];                       \
        float p4 = pbuf[BUF][4][bl][mtw], p5 = pbuf[BUF][5][bl][mtw];                       \
        float p6 = pbuf[BUF][6][bl][mtw], p7 = pbuf[BUF][7][bl][mtw];                       \
        float pre = (((p0 + p1) + (p2 + p3)) + ((p4 + p5) + (p6 + p7))) + xw;               \
        /* tanh(x) = 2/(1+2^(c*x)) - 1, c = -2*log2(e) */                                   \
        float e = __builtin_amdgcn_exp2f(-2.885390082f * pre);                              \
        float rr = __builtin_amdgcn_rcpf(1.0f + e);                                         \
        float hv = fmaf(2.0f, rr, -1.0f);                                                   \
        f16 hf = (f16)hv;                                                                   \
        if (lane < 32) {                                                                    \
            htp[(size_t)(T) * 256] = hf;                                                    \
            if ((T) == TT - 1) hlast[b * 256 + d] = hv;                                     \
        }                                                                                   \
        /* repack pair (both pair-lanes end with {even,odd}) */                             \
        uint my = (uint)__builtin_bit_cast(ushort, hf);                                     \
        uint pt = dpp_xor1_u(my);                                                           \
        hpk = (lane & 1) ? ((my << 16) | pt) : ((pt << 16) | my);                           \
    }

    for (int t = 0; t < TT; t += 2) {
        RNN_STEP(0, t)
        RNN_STEP(1, t + 1)
    }
#undef RNN_STEP
}

// ============ MFMA MLP: 4096 blocks x 256 threads, 64 tokens/block ============
struct MlpB {
    const uint4v* bf[7];
    const float* bias[7];
};

template <int KS, int NT, bool MSPLIT>
__device__ __forceinline__ void mfma_layer(const uint4v* __restrict__ Bf,
                                           const float* __restrict__ bias, int Nreal,
                                           const uint4v* zin, uint4v* zout,
                                           int w, int lane, int m15, int q) {
    constexpr int NW = MSPLIT ? NT : (NT / 4);  // n-tiles per wave
    constexpr int MW = MSPLIT ? 1 : 4;          // m-tiles per wave
    const int ntb = MSPLIT ? 0 : w * NW;
    const int mtb = MSPLIT ? w : 0;
    f32x4 acc[MW][NW];
#pragma unroll
    for (int i = 0; i < MW; ++i)
#pragma unroll
        for (int j = 0; j < NW; ++j) acc[i][j] = (f32x4){0.f, 0.f, 0.f, 0.f};

#pragma unroll
    for (int ks = 0; ks < KS; ++ks) {
        f16x8 a[MW];
#pragma unroll
        for (int mt = 0; mt < MW; ++mt)
            a[mt] = __builtin_bit_cast(f16x8, zin[((mtb + mt) * 16 + m15) * 37 + ks * 4 + q]);
#pragma unroll
        for (int nt = 0; nt < NW; ++nt) {
            f16x8 b = __builtin_bit_cast(f16x8, Bf[((size_t)(ntb + nt) * KS + ks) * 64 + lane]);
#pragma unroll
            for (int mt = 0; mt < MW; ++mt)
                acc[mt][nt] =
                    __builtin_amdgcn_mfma_f32_16x16x32_f16(a[mt], b, acc[mt][nt], 0, 0, 0);
        }
    }
    f16* zo = (f16*)zout;
#pragma unroll
    for (int nt = 0; nt < NW; ++nt) {
        const int col = (ntb + nt) * 16 + m15;
        const float bv = (col < Nreal) ? bias[col] : 0.f;
#pragma unroll
        for (int mt = 0; mt < MW; ++mt) {
#pragma unroll
            for (int r = 0; r < 4; ++r) {
                float v = acc[mt][nt][r] + bv;
                v = fmaxf(v, 0.01f * v);  // leaky relu
                const int row = (mtb + mt) * 16 + q * 4 + r;
                zo[row * 296 + col] = (f16)v;
            }
        }
    }
}

__global__ __launch_bounds__(256) void mlp_kernel(const f16* __restrict__ ht,
                                                  const float* __restrict__ x,
                                                  MlpB P, float* __restrict__ out) {
    __shared__ uint4v z0[64 * 37];  // 37888 B each; ping-pong
    __shared__ uint4v z1[64 * 37];
    const int tid = threadIdx.x;
    const int w = tid >> 6, lane = tid & 63;
    const int m15 = lane & 15, q = lane >> 4;
    const int tok0 = blockIdx.x * 64;

    // stage z0 = [ht(256) | x_fixed(5) | 0-pad(27)] rows, 296-f16 stride
    for (int i = tid; i < 64 * 32; i += 256) {
        int r = i >> 5, u = i & 31;
        z0[r * 37 + u] = ((const uint4v*)(ht + (size_t)(tok0 + r) * 256))[u];
    }
    for (int i = tid; i < 64 * 5; i += 256) {
        int r = i / 5, u = 32 + (i % 5);
        uint4v v = {0u, 0u, 0u, 0u};
        if (u == 32) {
            const float* xp = x + (size_t)(tok0 + r) * 12 + 7;
            v.x = packf16(xp[0], xp[1]);
            v.y = packf16(xp[2], xp[3]);
            v.z = packf16(xp[4], 0.f);
        }
        z0[r * 37 + u] = v;
    }
    __syncthreads();

    mfma_layer<9, 16, false>(P.bf[0], P.bias[0], 256, z0, z1, w, lane, m15, q);
    __syncthreads();
    mfma_layer<8, 8, false>(P.bf[1], P.bias[1], 128, z1, z0, w, lane, m15, q);
    __syncthreads();
    mfma_layer<4, 4, false>(P.bf[2], P.bias[2], 64, z0, z1, w, lane, m15, q);
    __syncthreads();
    mfma_layer<2, 2, true>(P.bf[3], P.bias[3], 32, z1, z0, w, lane, m15, q);
    __syncthreads();
    mfma_layer<1, 1, true>(P.bf[4], P.bias[4], 16, z0, z1, w, lane, m15, q);
    __syncthreads();
    mfma_layer<1, 1, true>(P.bf[5], P.bias[5], 8, z1, z0, w, lane, m15, q);
    __syncthreads();

    // L6 head: K=8 (padded 32), N=7; no activation; fp32 out
    {
        f16x8 a = __builtin_bit_cast(f16x8, z0[(w * 16 + m15) * 37 + q]);
        f16x8 b = __builtin_bit_cast(f16x8, P.bf[6][lane]);
        f32x4 acc = (f32x4){0.f, 0.f, 0.f, 0.f};
        acc = __builtin_amdgcn_mfma_f32_16x16x32_f16(a, b, acc, 0, 0, 0);
        if (m15 < 7) {
            const float bv = P.bias[6][m15];
#pragma unroll
            for (int r = 0; r < 4; ++r)
                out[(size_t)(tok0 + w * 16 + q * 4 + r) * 7 + m15] = acc[r] + bv;
        }
    }
}

// ============ launch ============
extern "C" void kernel_launch(void* const* d_in, const int* in_sizes, int n_in,
                              void* d_out, int out_size, void* d_ws, size_t ws_size,
                              hipStream_t stream) {
    const float* x = (const float*)d_in[0];
    const float* Wih = (const float*)d_in[1];
    const float* Whh = (const float*)d_in[2];
    const float* bih = (const float*)d_in[3];
    const float* bhh = (const float*)d_in[4];
    const float* W[7];
    const float* bb[7];
    for (int j = 0; j < 7; ++j) {
        W[j] = (const float*)d_in[5 + 2 * j];
        bb[j] = (const float*)d_in[6 + 2 * j];
    }
    float* out = (float*)d_out;

    static const int Kd[7] = {261, 256, 128, 64, 32, 16, 8};
    static const int Nd[7] = {256, 128, 64, 32, 16, 8, 7};
    static const int KSd[7] = {9, 8, 4, 2, 1, 1, 1};
    static const int NTd[7] = {16, 8, 4, 2, 1, 1, 1};

    char* ws = (char*)d_ws;
    f16* ht = (f16*)ws;  // 128 MiB, plain [b][t][j]
    size_t off = (size_t)NTOK * HH * 2;
    uint4v* Wsw = (uint4v*)(ws + off);
    off += (size_t)8192 * 16;
    uint4v* bfp[7];
    for (int j = 0; j < 7; ++j) {
        bfp[j] = (uint4v*)(ws + off);
        off += (size_t)NTd[j] * KSd[j] * 64 * 16;
    }

    rnn_wswz_kernel<<<32, 256, 0, stream>>>(Whh, Wsw);
    for (int j = 0; j < 7; ++j) {
        int cnt = NTd[j] * KSd[j] * 64;
        bfrag_prep_kernel<<<(cnt + 255) / 256, 256, 0, stream>>>(W[j], bfp[j], Nd[j], Kd[j],
                                                                 KSd[j], NTd[j]);
    }

    rnn_kernel<<<BB, 512, 0, stream>>>(x, Wsw, Wih, bih, bhh, ht, out + (size_t)NTOK * 7);

    MlpB P;
    for (int j = 0; j < 7; ++j) {
        P.bf[j] = bfp[j];
        P.bias[j] = bb[j];
    }
    mlp_kernel<<<NTOK / 64, 256, 0, stream>>>(ht, x, P, out);
}

// Round 8
// 2145.309 us; speedup vs baseline: 1.8619x; 1.1827x over previous
//
#include <hip/hip_runtime.h>

#define BB 64
#define TT 4096
#define HH 256
#define NTOK (BB * TT)

typedef _Float16 f16;
typedef _Float16 f16x8 __attribute__((ext_vector_type(8)));
typedef float f32x4 __attribute__((ext_vector_type(4)));
typedef unsigned int uint;
typedef unsigned short ushort;
typedef uint uint4v __attribute__((ext_vector_type(4)));

__device__ __forceinline__ uint packf16(float a, float b) {  // RNE pack (prep only)
    ushort lo = __builtin_bit_cast(ushort, (f16)a);
    ushort hi = __builtin_bit_cast(ushort, (f16)b);
    return (uint)lo | ((uint)hi << 16);
}

// ============ prep: W_hh -> MFMA A-fragment-major, per-RNN-thread contiguous ============
// RNN (256-thread) thread tid (lane=tid&63, w=tid>>6) holds frags fi = mt*8+ks
// (mt<4 m-tiles, ks<8 k-slices). Frag elem j:
// A[m=lane&15][k=32ks+8*(lane>>4)+j] = Whh[64w+16mt+(lane&15)][k].
__global__ __launch_bounds__(256) void rnn_wswz_kernel(const float* __restrict__ Whh,
                                                       uint4v* __restrict__ Wsw) {
    int gid = blockIdx.x * 256 + threadIdx.x;  // 8192 uint4 = 128 KiB
    if (gid >= 8192) return;
    int tid = gid >> 5, fi = gid & 31;
    int mt = fi >> 3, ks = fi & 7;
    int lane = tid & 63, w = tid >> 6;
    int hd = w * 64 + mt * 16 + (lane & 15);
    int kb = ks * 32 + ((lane >> 4) << 3);
    const float* p = Whh + hd * 256 + kb;
    uint4v v;
    v.x = packf16(p[0], p[1]);
    v.y = packf16(p[2], p[3]);
    v.z = packf16(p[4], p[5]);
    v.w = packf16(p[6], p[7]);
    Wsw[gid] = v;
}

// ============ prep: MLP weights -> MFMA B-fragment-major layout ============
__global__ __launch_bounds__(256) void bfrag_prep_kernel(const float* __restrict__ W,
                                                         uint4v* __restrict__ dst,
                                                         int N, int Kreal, int KS, int NT) {
    int gid = blockIdx.x * 256 + threadIdx.x;
    if (gid >= NT * KS * 64) return;
    int lane = gid & 63;
    int t = gid >> 6;
    int ks = t % KS, nt = t / KS;
    int n = nt * 16 + (lane & 15);
    int kb = ks * 32 + (lane >> 4) * 8;
    float f[8];
#pragma unroll
    for (int j = 0; j < 8; ++j) {
        int k = kb + j;
        f[j] = (n < N && k < Kreal) ? W[n * Kreal + k] : 0.f;
    }
    uint4v v;
    v.x = packf16(f[0], f[1]);
    v.y = packf16(f[2], f[3]);
    v.z = packf16(f[4], f[5]);
    v.w = packf16(f[6], f[7]);
    dst[gid] = v;
}

// ============ RNN: 64 blocks x 256 threads, MFMA recurrence, W in AGPRs ============
// 1 wave/SIMD (no same-phase issue contention). Wave w owns rows [64w,64w+64):
// A-frags wv[mt*8+ks] pinned to 128 AGPRs ("+a") -- MFMA reads A from AGPR natively,
// VGPRs stay free for hfr/acc/temps (~90). B = h from LDS, broadcast across 16 cols.
// D lane (q=lane>>4, bl=lane&15): acc[mt][r] = pre[64w+16mt+4q+r] (all bl dup).
// Extract mt=bl>>2, r=bl&3 -> d = 64w+16(bl>>2)+4q+(bl&3): bijection over the wave's 64.
__global__ __launch_bounds__(256) __attribute__((amdgpu_waves_per_eu(1, 1))) void rnn_kernel(
        const float* __restrict__ x, const uint4v* __restrict__ Wsw,
        const float* __restrict__ Wih, const float* __restrict__ bih,
        const float* __restrict__ bhh, f16* __restrict__ ht, float* __restrict__ hlast) {
    const int b = blockIdx.x, tid = threadIdx.x;
    const int lane = tid & 63, w = tid >> 6;
    const int q = lane >> 4, bl = lane & 15;
    const int d = w * 64 + ((bl >> 2) << 4) + (q << 2) + (bl & 3);  // this lane's hdim
    __shared__ __align__(16) f16 hbuf[2][256];  // double-buffered h
    __shared__ uint4 xs[2][128];                // 64 timesteps x 32B, double-buffered

    uint4v wv[32];  // A-frags: wv[mt*8+ks] -> AGPRs
    {
        const uint4v* wp = Wsw + (size_t)tid * 32;
#pragma unroll
        for (int i = 0; i < 32; ++i) wv[i] = wp[i];
    }
#pragma unroll
    for (int i = 0; i < 32; ++i) asm volatile("" : "+a"(wv[i]));  // pin to AGPR file

    float wih[7];
#pragma unroll
    for (int i = 0; i < 7; ++i) wih[i] = Wih[d * 7 + i];
    const float bias = bih[d] + bhh[d];

    const float* xb = x + (size_t)b * TT * 12;
    uint4 xpre = make_uint4(0, 0, 0, 0);
    if (tid < 128) {
        int row = tid >> 1, u = tid & 1;
        xs[0][row * 2 + u] = *(const uint4*)(xb + row * 12 + u * 4);
        xpre = *(const uint4*)(xb + (64 + row) * 12 + u * 4);
        ((uint*)hbuf[0])[tid] = 0;  // zero h0
    }
    __syncthreads();

    f16* htp = ht + (size_t)b * TT * 256 + d;  // PLAIN layout [b][t][j]
    ushort hst[16];

    for (int tb = 0; tb < 256; ++tb) {
#pragma unroll
        for (int k = 0; k < 16; ++k) {
            const int t = tb * 16 + k;
            const int cur = k & 1;
            const int tile = (t >> 6) & 1, tstep = t & 63;

            // B-frags FIRST (critical path): h[32ks+8q..+8), pure broadcast reads
            const uint4v* hq = (const uint4v*)hbuf[cur];
            uint4v hfr[8];
#pragma unroll
            for (int ks = 0; ks < 8; ++ks) hfr[ks] = hq[ks * 4 + q];

            // 4 independent acc chains (mt), round-robin over ks: dep spacing 4
            f32x4 acc[4];
#pragma unroll
            for (int mt = 0; mt < 4; ++mt) acc[mt] = (f32x4){0.f, 0.f, 0.f, 0.f};
#pragma unroll
            for (int ks = 0; ks < 8; ++ks) {
                f16x8 hb = __builtin_bit_cast(f16x8, hfr[ks]);
#pragma unroll
                for (int mt = 0; mt < 4; ++mt)
                    acc[mt] = __builtin_amdgcn_mfma_f32_16x16x32_f16(
                        __builtin_bit_cast(f16x8, wv[mt * 8 + ks]), hb, acc[mt], 0, 0, 0);
            }

            // x contribution (VALU co-issues with matrix pipe)
            const float4 xa = ((const float4*)xs[tile])[tstep * 2];
            const float4 xc = ((const float4*)xs[tile])[tstep * 2 + 1];
            float xw = fmaf(xa.x, wih[0], bias);
            xw = fmaf(xa.y, wih[1], xw);
            xw = fmaf(xa.z, wih[2], xw);
            xw = fmaf(xa.w, wih[3], xw);
            xw = fmaf(xc.x, wih[4], xw);
            xw = fmaf(xc.y, wih[5], xw);
            xw = fmaf(xc.z, wih[6], xw);

            // extract acc[bl>>2][bl&3]: 15 cndmask
            float t0[4];
#pragma unroll
            for (int mt = 0; mt < 4; ++mt) {
                float a01 = (bl & 1) ? acc[mt][1] : acc[mt][0];
                float a23 = (bl & 1) ? acc[mt][3] : acc[mt][2];
                t0[mt] = (bl & 2) ? a23 : a01;
            }
            float u0 = (bl & 4) ? t0[1] : t0[0];
            float u1 = (bl & 4) ? t0[3] : t0[2];
            float pre = ((bl & 8) ? u1 : u0) + xw;

            // tanh(x) = 2/(1+2^(c*x)) - 1, c = -2*log2(e)
            float e = __builtin_amdgcn_exp2f(-2.885390082f * pre);
            float rr = __builtin_amdgcn_rcpf(1.0f + e);
            float h = fmaf(2.0f, rr, -1.0f);

            f16 hf = (f16)h;
            hbuf[cur ^ 1][d] = hf;  // 64 distinct dims/wave, 2B, 2-way alias = free
            hst[k] = __builtin_bit_cast(ushort, hf);
            if (tb == 255 && k == 15) hlast[b * 256 + d] = h;

            if (tstep == 32 && tid < 128) {
                int row = tid >> 1, u = tid & 1;
                xs[tile ^ 1][row * 2 + u] = xpre;
                int nt = (t & ~63) + 128 + row;
                if (nt > TT - 1) nt = TT - 1;
                xpre = *(const uint4*)(xb + nt * 12 + u * 4);
            }
            asm volatile("s_waitcnt lgkmcnt(0)\n\ts_barrier" ::: "memory");
        }
        const size_t base = (size_t)(tb * 16) * 256;
#pragma unroll
        for (int k = 0; k < 16; ++k)
            htp[base + (size_t)k * 256] = __builtin_bit_cast(f16, hst[k]);
    }
}

// ============ MFMA MLP: 4096 blocks x 256 threads, 64 tokens/block ============
struct MlpB {
    const uint4v* bf[7];
    const float* bias[7];
};

template <int KS, int NT, bool MSPLIT>
__device__ __forceinline__ void mfma_layer(const uint4v* __restrict__ Bf,
                                           const float* __restrict__ bias, int Nreal,
                                           const uint4v* zin, uint4v* zout,
                                           int w, int lane, int m15, int q) {
    constexpr int NW = MSPLIT ? NT : (NT / 4);  // n-tiles per wave
    constexpr int MW = MSPLIT ? 1 : 4;          // m-tiles per wave
    const int ntb = MSPLIT ? 0 : w * NW;
    const int mtb = MSPLIT ? w : 0;
    f32x4 acc[MW][NW];
#pragma unroll
    for (int i = 0; i < MW; ++i)
#pragma unroll
        for (int j = 0; j < NW; ++j) acc[i][j] = (f32x4){0.f, 0.f, 0.f, 0.f};

#pragma unroll
    for (int ks = 0; ks < KS; ++ks) {
        f16x8 a[MW];
#pragma unroll
        for (int mt = 0; mt < MW; ++mt)
            a[mt] = __builtin_bit_cast(f16x8, zin[((mtb + mt) * 16 + m15) * 37 + ks * 4 + q]);
#pragma unroll
        for (int nt = 0; nt < NW; ++nt) {
            f16x8 b = __builtin_bit_cast(f16x8, Bf[((size_t)(ntb + nt) * KS + ks) * 64 + lane]);
#pragma unroll
            for (int mt = 0; mt < MW; ++mt)
                acc[mt][nt] =
                    __builtin_amdgcn_mfma_f32_16x16x32_f16(a[mt], b, acc[mt][nt], 0, 0, 0);
        }
    }
    f16* zo = (f16*)zout;
#pragma unroll
    for (int nt = 0; nt < NW; ++nt) {
        const int col = (ntb + nt) * 16 + m15;
        const float bv = (col < Nreal) ? bias[col] : 0.f;
#pragma unroll
        for (int mt = 0; mt < MW; ++mt) {
#pragma unroll
            for (int r = 0; r < 4; ++r) {
                float v = acc[mt][nt][r] + bv;
                v = fmaxf(v, 0.01f * v);  // leaky relu
                const int row = (mtb + mt) * 16 + q * 4 + r;
                zo[row * 296 + col] = (f16)v;
            }
        }
    }
}

__global__ __launch_bounds__(256) void mlp_kernel(const f16* __restrict__ ht,
                                                  const float* __restrict__ x,
                                                  MlpB P, float* __restrict__ out) {
    __shared__ uint4v z0[64 * 37];  // 37888 B each; ping-pong
    __shared__ uint4v z1[64 * 37];
    const int tid = threadIdx.x;
    const int w = tid >> 6, lane = tid & 63;
    const int m15 = lane & 15, q = lane >> 4;
    const int tok0 = blockIdx.x * 64;

    // stage z0 = [ht(256) | x_fixed(5) | 0-pad(27)] rows, 296-f16 stride
    for (int i = tid; i < 64 * 32; i += 256) {
        int r = i >> 5, u = i & 31;
        z0[r * 37 + u] = ((const uint4v*)(ht + (size_t)(tok0 + r) * 256))[u];
    }
    for (int i = tid; i < 64 * 5; i += 256) {
        int r = i / 5, u = 32 + (i % 5);
        uint4v v = {0u, 0u, 0u, 0u};
        if (u == 32) {
            const float* xp = x + (size_t)(tok0 + r) * 12 + 7;
            v.x = packf16(xp[0], xp[1]);
            v.y = packf16(xp[2], xp[3]);
            v.z = packf16(xp[4], 0.f);
        }
        z0[r * 37 + u] = v;
    }
    __syncthreads();

    mfma_layer<9, 16, false>(P.bf[0], P.bias[0], 256, z0, z1, w, lane, m15, q);
    __syncthreads();
    mfma_layer<8, 8, false>(P.bf[1], P.bias[1], 128, z1, z0, w, lane, m15, q);
    __syncthreads();
    mfma_layer<4, 4, false>(P.bf[2], P.bias[2], 64, z0, z1, w, lane, m15, q);
    __syncthreads();
    mfma_layer<2, 2, true>(P.bf[3], P.bias[3], 32, z1, z0, w, lane, m15, q);
    __syncthreads();
    mfma_layer<1, 1, true>(P.bf[4], P.bias[4], 16, z0, z1, w, lane, m15, q);
    __syncthreads();
    mfma_layer<1, 1, true>(P.bf[5], P.bias[5], 8, z1, z0, w, lane, m15, q);
    __syncthreads();

    // L6 head: K=8 (padded 32), N=7; no activation; fp32 out
    {
        f16x8 a = __builtin_bit_cast(f16x8, z0[(w * 16 + m15) * 37 + q]);
        f16x8 b = __builtin_bit_cast(f16x8, P.bf[6][lane]);
        f32x4 acc = (f32x4){0.f, 0.f, 0.f, 0.f};
        acc = __builtin_amdgcn_mfma_f32_16x16x32_f16(a, b, acc, 0, 0, 0);
        if (m15 < 7) {
            const float bv = P.bias[6][m15];
#pragma unroll
            for (int r = 0; r < 4; ++r)
                out[(size_t)(tok0 + w * 16 + q * 4 + r) * 7 + m15] = acc[r] + bv;
        }
    }
}

// ============ launch ============
extern "C" void kernel_launch(void* const* d_in, const int* in_sizes, int n_in,
                              void* d_out, int out_size, void* d_ws, size_t ws_size,
                              hipStream_t stream) {
    const float* x = (const float*)d_in[0];
    const float* Wih = (const float*)d_in[1];
    const float* Whh = (const float*)d_in[2];
    const float* bih = (const float*)d_in[3];
    const float* bhh = (const float*)d_in[4];
    const float* W[7];
    const float* bb[7];
    for (int j = 0; j < 7; ++j) {
        W[j] = (const float*)d_in[5 + 2 * j];
        bb[j] = (const float*)d_in[6 + 2 * j];
    }
    float* out = (float*)d_out;

    static const int Kd[7] = {261, 256, 128, 64, 32, 16, 8};
    static const int Nd[7] = {256, 128, 64, 32, 16, 8, 7};
    static const int KSd[7] = {9, 8, 4, 2, 1, 1, 1};
    static const int NTd[7] = {16, 8, 4, 2, 1, 1, 1};

    char* ws = (char*)d_ws;
    f16* ht = (f16*)ws;  // 128 MiB, plain [b][t][j]
    size_t off = (size_t)NTOK * HH * 2;
    uint4v* Wsw = (uint4v*)(ws + off);
    off += (size_t)8192 * 16;
    uint4v* bfp[7];
    for (int j = 0; j < 7; ++j) {
        bfp[j] = (uint4v*)(ws + off);
        off += (size_t)NTd[j] * KSd[j] * 64 * 16;
    }

    rnn_wswz_kernel<<<32, 256, 0, stream>>>(Whh, Wsw);
    for (int j = 0; j < 7; ++j) {
        int cnt = NTd[j] * KSd[j] * 64;
        bfrag_prep_kernel<<<(cnt + 255) / 256, 256, 0, stream>>>(W[j], bfp[j], Nd[j], Kd[j],
                                                                 KSd[j], NTd[j]);
    }

    rnn_kernel<<<BB, 256, 0, stream>>>(x, Wsw, Wih, bih, bhh, ht, out + (size_t)NTOK * 7);

    MlpB P;
    for (int j = 0; j < 7; ++j) {
        P.bf[j] = bfp[j];
        P.bias[j] = bb[j];
    }
    mlp_kernel<<<NTOK / 64, 256, 0, stream>>>(ht, x, P, out);
}